// Round 1
// baseline (278.030 us; speedup 1.0000x reference)
//
#include <hip/hip_runtime.h>

// Sparse 2:4 grouped conv, MI355X.
// B=32, CIN=256, H=W=56, COUT=256, 3x3 s1 p1, G=2 -> per-group GEMM 128x1152x100352.
// Pipeline: (1) mask+pack W -> bf16 [g][tap][of][c]; (2) pad+transpose x -> bf16
// [bg][58][58][c]; (3) m97-style implicit-GEMM with 16x16x32 bf16 MFMA.

#define INF   1152
#define HO    56
#define LOUT  3136      // 56*56
#define XP    58        // padded spatial

typedef __attribute__((ext_vector_type(8))) short bf16x8;
typedef __attribute__((ext_vector_type(4))) float f32x4;

__device__ __forceinline__ unsigned short f2bf(float f) {
  union { float f; unsigned u; } v; v.f = f;
  unsigned r = v.u + 0x7fffu + ((v.u >> 16) & 1u);   // RNE
  return (unsigned short)(r >> 16);
}

__device__ __forceinline__ void async_load16(const void* g, void* l) {
  __builtin_amdgcn_global_load_lds(
      (const __attribute__((address_space(1))) void*)g,
      (__attribute__((address_space(3))) void*)l, 16, 0, 0);
}

// ---------------- kernel 1: gumbel-argmax mask + pack/reorder weights ----------------
// out layout: Wt[g][tap(9)][of(128)][c(128)] bf16.  idx=((g*9+tap)*128+of)*128+c
__global__ __launch_bounds__(256) void mask_pack_kernel(
    const float* __restrict__ Ws, const float* __restrict__ cw,
    const float* __restrict__ gb, const float* __restrict__ pat,
    unsigned short* __restrict__ Wt) {
  int idx = blockIdx.x * 256 + threadIdx.x;       // 294912 total
  int c   = idx & 127;
  int of  = (idx >> 7) & 127;
  int gt  = idx >> 14;                            // g*9+tap
  int g   = gt / 9;
  int tap = gt - g * 9;
  int e   = ((g << 7) + of) * INF + c * 9 + tap;  // flat index into Ws / mask
  int q   = e >> 2;
  int pos = e & 3;
  const float* cq = cw + q * 6;
  const float* gq = gb + q * 6;
  float best = cq[0] + gq[0]; int bi = 0;
  #pragma unroll
  for (int j = 1; j < 6; ++j) {
    float v = cq[j] + gq[j];
    if (v > best) { best = v; bi = j; }           // strict > = first-max, matches argmax
  }
  float m = pat[bi * 4 + pos];
  Wt[idx] = f2bf(Ws[e] * m);
}

// ---------------- kernel 2: pad + transpose + cast x ----------------
// x (B,256,56,56) f32  ->  Xt[bg(64)][ihp(58)][iwp(58)][c(128)] bf16, zero borders.
__global__ __launch_bounds__(256) void xpose_kernel(const float* __restrict__ x,
                                                    unsigned short* __restrict__ Xt) {
  __shared__ float lds[56 * 129];                 // [iw][c], pad stride 129
  const int t   = threadIdx.x;
  const int ihp = blockIdx.x;                     // 0..57
  const int bg  = blockIdx.y;                     // b*2+g, 0..63
  unsigned int* dst = (unsigned int*)(Xt + ((bg * XP + ihp) * XP) * 128); // pair-packed
  if (ihp == 0 || ihp == XP - 1) {
    for (int i = t; i < XP * 64; i += 256) dst[i] = 0u;   // whole padded row = 0
    return;
  }
  const int ih = ihp - 1;
  const float* src = x + (bg * 128) * LOUT + ih * HO;     // + c*3136 + iw
  for (int i = t; i < 128 * HO; i += 256) {               // coalesced along iw
    int c = i / HO, iw = i - c * HO;
    lds[iw * 129 + c] = src[c * LOUT + iw];
  }
  __syncthreads();
  for (int i = t; i < XP * 64; i += 256) {                // pair (c,c+1) per thread
    int iwp = i >> 6;
    int cp  = i & 63;
    unsigned int val = 0;
    if (iwp != 0 && iwp != XP - 1) {
      int iw = iwp - 1, c = cp << 1;
      unsigned lo = f2bf(lds[iw * 129 + c]);
      unsigned hi = f2bf(lds[iw * 129 + c + 1]);
      val = lo | (hi << 16);
    }
    dst[i] = val;
  }
}

// ---------------- kernel 3: implicit-GEMM conv, bf16 MFMA ----------------
// Block: 256 thr, tile M=128(of) x N=128(l), K-loop 9 taps x 4 chunks of 32(c).
__global__ __launch_bounds__(256, 2) void conv_mfma_kernel(
    const unsigned short* __restrict__ Wt, const unsigned short* __restrict__ Xt,
    float* __restrict__ out) {
  __shared__ __align__(16) unsigned short sA[128 * 32];   // [of][c]
  __shared__ __align__(16) unsigned short sB[128 * 32];   // [l_local][c]
  const int t  = threadIdx.x;
  const int ln = t & 63, wv = t >> 6;
  const int wm = wv >> 1, wn = wv & 1;
  const int col = ln & 15, kq = ln >> 4;
  const int tileN = blockIdx.x;                   // 0..24
  const int bg    = blockIdx.y;                   // 0..63
  const int g     = bg & 1;
  const int l0    = tileN << 7;

  // staging geometry: thread t stages 8 c's for row (t>>2) (+64 for pass 1)
  const int c8   = (t & 3) << 3;
  const int aoff = ((t >> 2) << 7) + c8;          // of*128 + c8
  int boff[2];
  #pragma unroll
  for (int p = 0; p < 2; ++p) {
    int ll = l0 + (p << 6) + (t >> 2);
    if (ll > LOUT - 1) ll = LOUT - 1;             // tail tile: clamp (stores guarded)
    int oh = ll / HO, ow = ll - oh * HO;
    boff[p] = ((bg * XP + oh) * XP + ow) * 128 + c8;
  }
  const int ldsw = (wv << 9);                     // wave slice within a pass (elems)

  f32x4 acc[4][4];
  #pragma unroll
  for (int i = 0; i < 4; ++i)
    #pragma unroll
    for (int j = 0; j < 4; ++j) acc[i][j] = (f32x4){0.f, 0.f, 0.f, 0.f};

  for (int tap = 0; tap < 9; ++tap) {
    const int th = tap / 3, tw = tap - th * 3;
    const int bTap = (th * XP + tw) << 7;         // *128
    const int aTap = (g * 9 + tap) << 14;         // *16384
    #pragma unroll 1
    for (int kc = 0; kc < 4; ++kc) {
      const int c0 = kc << 5;
      __syncthreads();                            // prior reads done before overwrite
      #pragma unroll
      for (int p = 0; p < 2; ++p) {
        async_load16(Wt + aTap + (p << 13) + aoff + c0, &sA[(p << 11) + ldsw]);
        async_load16(Xt + boff[p] + bTap + c0,          &sB[(p << 11) + ldsw]);
      }
      __syncthreads();                            // compiler drains vmcnt before barrier
      bf16x8 af[4], bfr[4];
      #pragma unroll
      for (int mi = 0; mi < 4; ++mi)
        af[mi] = *(const bf16x8*)&sA[(((wm << 6) + (mi << 4) + col) << 5) + (kq << 3)];
      #pragma unroll
      for (int ni = 0; ni < 4; ++ni)
        bfr[ni] = *(const bf16x8*)&sB[(((wn << 6) + (ni << 4) + col) << 5) + (kq << 3)];
      #pragma unroll
      for (int mi = 0; mi < 4; ++mi)
        #pragma unroll
        for (int ni = 0; ni < 4; ++ni)
          acc[mi][ni] = __builtin_amdgcn_mfma_f32_16x16x32_bf16(
              af[mi], bfr[ni], acc[mi][ni], 0, 0, 0);
    }
  }

  // epilogue: C/D layout col=lane&15, row=(lane>>4)*4+reg  (m89/m91-verified)
  const int rowq = kq << 2;
  #pragma unroll
  for (int mi = 0; mi < 4; ++mi) {
    #pragma unroll
    for (int ni = 0; ni < 4; ++ni) {
      const int l = l0 + (wn << 6) + (ni << 4) + col;
      if (l < LOUT) {
        #pragma unroll
        for (int r = 0; r < 4; ++r) {
          const int of = (wm << 6) + (mi << 4) + rowq + r;
          out[(bg * 128 + of) * LOUT + l] = acc[mi][ni][r];
        }
      }
    }
  }
}

extern "C" void kernel_launch(void* const* d_in, const int* in_sizes, int n_in,
                              void* d_out, int out_size, void* d_ws, size_t ws_size,
                              hipStream_t stream) {
  const float* x   = (const float*)d_in[0];
  const float* Ws  = (const float*)d_in[1];
  const float* cw  = (const float*)d_in[2];
  const float* gb  = (const float*)d_in[3];
  const float* pat = (const float*)d_in[4];
  float* out = (float*)d_out;

  unsigned short* Wt = (unsigned short*)d_ws;                       // 294912 bf16 = 576 KB
  unsigned short* Xt = (unsigned short*)((char*)d_ws + (1 << 20));  // 27.56M bf16 = 52.6 MB

  mask_pack_kernel<<<1152, 256, 0, stream>>>(Ws, cw, gb, pat, Wt);
  xpose_kernel<<<dim3(XP, 64), 256, 0, stream>>>(x, Xt);
  conv_mfma_kernel<<<dim3(25, 64), 256, 0, stream>>>(Wt, Xt, out);
}

// Round 2
// 278.002 us; speedup vs baseline: 1.0001x; 1.0001x over previous
//
#include <hip/hip_runtime.h>

// Sparse 2:4 grouped conv, MI355X.  R2: LDS xor-swizzle in conv (kill 8-way
// bank conflicts), vectorized xpose, split mask argmax, XCD-aware block swizzle.

#define INF   1152
#define HO    56
#define LOUT  3136      // 56*56
#define XP    58        // padded spatial
#define Q     73728

typedef __attribute__((ext_vector_type(8))) short bf16x8;
typedef __attribute__((ext_vector_type(4))) float f32x4;

__device__ __forceinline__ unsigned short f2bf(float f) {
  union { float f; unsigned u; } v; v.f = f;
  unsigned r = v.u + 0x7fffu + ((v.u >> 16) & 1u);   // RNE
  return (unsigned short)(r >> 16);
}

__device__ __forceinline__ void async_load16(const void* g, void* l) {
  __builtin_amdgcn_global_load_lds(
      (const __attribute__((address_space(1))) void*)g,
      (__attribute__((address_space(3))) void*)l, 16, 0, 0);
}

// ---------------- kernel 1a: gumbel argmax per quadruplet ----------------
__global__ __launch_bounds__(256) void gumbel_kernel(
    const float* __restrict__ cw, const float* __restrict__ gb,
    unsigned char* __restrict__ pmask) {
  int q = blockIdx.x * 256 + threadIdx.x;          // 73728 exact
  const float* cq = cw + q * 6;
  const float* gq = gb + q * 6;
  float best = cq[0] + gq[0]; int bi = 0;
  #pragma unroll
  for (int j = 1; j < 6; ++j) {
    float v = cq[j] + gq[j];
    if (v > best) { best = v; bi = j; }            // strict > = first-max
  }
  pmask[q] = (unsigned char)bi;
}

// ---------------- kernel 1b: apply mask + pack/reorder weights ----------------
// out layout: Wt[g][tap(9)][of(128)][c(128)] bf16.
__global__ __launch_bounds__(256) void pack_kernel(
    const float* __restrict__ Ws, const unsigned char* __restrict__ pmask,
    const float* __restrict__ pat, unsigned short* __restrict__ Wt) {
  int idx = blockIdx.x * 256 + threadIdx.x;        // 294912 total
  int c   = idx & 127;
  int of  = (idx >> 7) & 127;
  int gt  = idx >> 14;                             // g*9+tap
  int g   = gt / 9;
  int tap = gt - g * 9;
  int e   = ((g << 7) + of) * INF + c * 9 + tap;   // flat index into Ws / mask
  float m = pat[pmask[e >> 2] * 4 + (e & 3)];
  Wt[idx] = f2bf(Ws[e] * m);
}

// ---------------- kernel 2: pad + transpose + cast x (vectorized) ----------------
// x (B,256,56,56) f32  ->  Xt[bg(64)][ihp(58)][iwp(58)][c(128)] bf16, zero borders.
__global__ __launch_bounds__(256) void xpose_kernel(const float* __restrict__ x,
                                                    unsigned short* __restrict__ Xt) {
  __shared__ float lds[56 * 129];                  // [iw][c], stride 129 floats
  const int t   = threadIdx.x;
  const int ihp = blockIdx.x;                      // 0..57
  const int bg  = blockIdx.y;                      // b*2+g, 0..63
  uint4* dst = (uint4*)(Xt + ((bg * XP + ihp) * XP) * 128);  // 16B-packed row
  if (ihp == 0 || ihp == XP - 1) {
    const uint4 z = {0u, 0u, 0u, 0u};
    for (int i = t; i < XP * 16; i += 256) dst[i] = z;       // whole row = 0
    return;
  }
  const int ih = ihp - 1;
  const float4* src = (const float4*)(x + (bg * 128) * LOUT + ih * HO);
  // load: 128 c-rows x 14 float4 each (row stride LOUT/4 float4s)
  for (int i = t; i < 128 * 14; i += 256) {
    int c = i / 14, seg = i - c * 14;              // iw = seg*4
    float4 v = src[c * (LOUT / 4) + seg];
    float* row = &lds[(seg * 4) * 129 + c];
    row[0]       = v.x;
    row[129]     = v.y;
    row[2 * 129] = v.z;
    row[3 * 129] = v.w;
  }
  __syncthreads();
  // store: 58 iwp x 16 octs, 16B per item
  for (int i = t; i < XP * 16; i += 256) {
    int iwp = i >> 4, oct = i & 15;
    uint4 val = {0u, 0u, 0u, 0u};
    if (iwp != 0 && iwp != XP - 1) {
      const float* s = &lds[(iwp - 1) * 129 + (oct << 3)];
      unsigned d0 = (unsigned)f2bf(s[0]) | ((unsigned)f2bf(s[1]) << 16);
      unsigned d1 = (unsigned)f2bf(s[2]) | ((unsigned)f2bf(s[3]) << 16);
      unsigned d2 = (unsigned)f2bf(s[4]) | ((unsigned)f2bf(s[5]) << 16);
      unsigned d3 = (unsigned)f2bf(s[6]) | ((unsigned)f2bf(s[7]) << 16);
      val.x = d0; val.y = d1; val.z = d2; val.w = d3;
    }
    dst[i] = val;
  }
}

// ---------------- kernel 3: implicit-GEMM conv, bf16 MFMA, xor-swizzled LDS ----
// LDS layout: 16B block (row,kq) stored at slot row*4 + (kq ^ ((row>>1)&3)).
__global__ __launch_bounds__(256, 4) void conv_mfma_kernel(
    const unsigned short* __restrict__ Wt, const unsigned short* __restrict__ Xt,
    float* __restrict__ out) {
  __shared__ __align__(16) unsigned short sA[128 * 32];
  __shared__ __align__(16) unsigned short sB[128 * 32];
  const int t  = threadIdx.x;
  const int ln = t & 63, wv = t >> 6;
  const int wm = wv >> 1, wn = wv & 1;
  const int col = ln & 15, kq = ln >> 4;

  // XCD-aware block swizzle: 1600 blocks, round-robin lid%8 -> give each XCD
  // a contiguous range of 8 bg's (25 tiles each) for L2 locality.
  const int lid   = blockIdx.y * 25 + blockIdx.x;
  const int v     = (lid & 7) * 200 + (lid >> 3);
  const int bg    = v / 25;
  const int tileN = v - bg * 25;
  const int g     = bg & 1;
  const int l0    = tileN << 7;

  // staging: thread t -> row (t>>2), swizzled kq chunk
  const int kqs  = (t & 3) ^ ((t >> 3) & 3);
  const int c8   = kqs << 3;
  const int aoff = ((t >> 2) << 7) + c8;           // of*128 + c8
  int boff[2];
  #pragma unroll
  for (int p = 0; p < 2; ++p) {
    int ll = l0 + (p << 6) + (t >> 2);
    if (ll > LOUT - 1) ll = LOUT - 1;              // tail tile: clamp
    int oh = ll / HO, ow = ll - oh * HO;
    boff[p] = ((bg * XP + oh) * XP + ow) * 128 + c8;
  }
  const int ldsw = (wv << 9);                      // wave slice (elements)
  const int swk  = (kq ^ ((col >> 1) & 3)) << 3;   // read-side swizzled k slot

  f32x4 acc[4][4];
  #pragma unroll
  for (int i = 0; i < 4; ++i)
    #pragma unroll
    for (int j = 0; j < 4; ++j) acc[i][j] = (f32x4){0.f, 0.f, 0.f, 0.f};

  for (int tap = 0; tap < 9; ++tap) {
    const int th = tap / 3, tw = tap - th * 3;
    const int bTap = (th * XP + tw) << 7;
    const int aTap = (g * 9 + tap) << 14;
    #pragma unroll 1
    for (int kc = 0; kc < 4; ++kc) {
      const int c0 = kc << 5;
      __syncthreads();
      #pragma unroll
      for (int p = 0; p < 2; ++p) {
        async_load16(Wt + aTap + (p << 13) + aoff + c0, &sA[(p << 11) + ldsw]);
        async_load16(Xt + boff[p] + bTap + c0,          &sB[(p << 11) + ldsw]);
      }
      __syncthreads();
      bf16x8 af[4], bfr[4];
      #pragma unroll
      for (int mi = 0; mi < 4; ++mi)
        af[mi] = *(const bf16x8*)&sA[(wm << 11) + (((mi << 4) + col) << 5) + swk];
      #pragma unroll
      for (int ni = 0; ni < 4; ++ni)
        bfr[ni] = *(const bf16x8*)&sB[(wn << 11) + (((ni << 4) + col) << 5) + swk];
      #pragma unroll
      for (int mi = 0; mi < 4; ++mi)
        #pragma unroll
        for (int ni = 0; ni < 4; ++ni)
          acc[mi][ni] = __builtin_amdgcn_mfma_f32_16x16x32_bf16(
              af[mi], bfr[ni], acc[mi][ni], 0, 0, 0);
    }
  }

  // epilogue: C/D layout col=lane&15, row=(lane>>4)*4+reg
  const int rowq = kq << 2;
  #pragma unroll
  for (int mi = 0; mi < 4; ++mi) {
    #pragma unroll
    for (int ni = 0; ni < 4; ++ni) {
      const int l = l0 + (wn << 6) + (ni << 4) + col;
      if (l < LOUT) {
        #pragma unroll
        for (int r = 0; r < 4; ++r) {
          const int of = (wm << 6) + (mi << 4) + rowq + r;
          out[(bg * 128 + of) * LOUT + l] = acc[mi][ni][r];
        }
      }
    }
  }
}

extern "C" void kernel_launch(void* const* d_in, const int* in_sizes, int n_in,
                              void* d_out, int out_size, void* d_ws, size_t ws_size,
                              hipStream_t stream) {
  const float* x   = (const float*)d_in[0];
  const float* Ws  = (const float*)d_in[1];
  const float* cw  = (const float*)d_in[2];
  const float* gb  = (const float*)d_in[3];
  const float* pat = (const float*)d_in[4];
  float* out = (float*)d_out;

  unsigned short* Wt    = (unsigned short*)d_ws;                        // 576 KB
  unsigned char*  pmask = (unsigned char*)((char*)d_ws + 640 * 1024);   // 72 KB
  unsigned short* Xt    = (unsigned short*)((char*)d_ws + (1 << 20));   // 52.6 MB

  gumbel_kernel<<<Q / 256, 256, 0, stream>>>(cw, gb, pmask);
  xpose_kernel<<<dim3(XP, 64), 256, 0, stream>>>(x, Xt);
  pack_kernel<<<1152, 256, 0, stream>>>(Ws, pmask, pat, Wt);
  conv_mfma_kernel<<<dim3(25, 64), 256, 0, stream>>>(Wt, Xt, out);
}

// Round 3
// 253.649 us; speedup vs baseline: 1.0961x; 1.0960x over previous
//
#include <hip/hip_runtime.h>

// Sparse 2:4 grouped conv, MI355X.  R3: BK=64 (half the barriers, 8 outstanding
// global_load_lds per drain), xor-swizzled LDS for the 64-c row, fused prep.

#define INF   1152
#define HO    56
#define LOUT  3136      // 56*56
#define XP    58        // padded spatial

typedef __attribute__((ext_vector_type(8))) short bf16x8;
typedef __attribute__((ext_vector_type(4))) float f32x4;

__device__ __forceinline__ unsigned short f2bf(float f) {
  union { float f; unsigned u; } v; v.f = f;
  unsigned r = v.u + 0x7fffu + ((v.u >> 16) & 1u);   // RNE
  return (unsigned short)(r >> 16);
}

__device__ __forceinline__ void async_load16(const void* g, void* l) {
  __builtin_amdgcn_global_load_lds(
      (const __attribute__((address_space(1))) void*)g,
      (__attribute__((address_space(3))) void*)l, 16, 0, 0);
}

// ---------------- fused prep: pad+transpose+cast x  |  gumbel+mask+pack W ------
// blocks [0,3712): xpose (bg=bid/58, ihp=bid%58)
// blocks [3712,4864): Wt[g][tap][of][c] pack with inline gumbel argmax
__global__ __launch_bounds__(256) void prep_kernel(
    const float* __restrict__ x, const float* __restrict__ Ws,
    const float* __restrict__ cw, const float* __restrict__ gb,
    const float* __restrict__ pat,
    unsigned short* __restrict__ Xt, unsigned short* __restrict__ Wt) {
  __shared__ float lds[56 * 129];
  const int t   = threadIdx.x;
  const int bid = blockIdx.x;

  if (bid >= 3712) {                                 // ---- weight pack ----
    int idx = (bid - 3712) * 256 + t;                // 294912 total
    int c   = idx & 127;
    int of  = (idx >> 7) & 127;
    int gt  = idx >> 14;                             // g*9+tap
    int g   = gt / 9;
    int tap = gt - g * 9;
    int e   = ((g << 7) + of) * INF + c * 9 + tap;
    int q   = e >> 2, pos = e & 3;
    const float* cq = cw + q * 6;
    const float* gq = gb + q * 6;
    float best = cq[0] + gq[0]; int bi = 0;
    #pragma unroll
    for (int j = 1; j < 6; ++j) {
      float v2 = cq[j] + gq[j];
      if (v2 > best) { best = v2; bi = j; }          // strict > = first-max
    }
    Wt[idx] = f2bf(Ws[e] * pat[bi * 4 + pos]);
    return;
  }

  // ---- xpose: x (B,256,56,56) f32 -> Xt[bg][58][58][c=128] bf16, zero borders
  const int bg  = bid / 58;
  const int ihp = bid - bg * 58;
  uint4* dst = (uint4*)(Xt + ((bg * XP + ihp) * XP) * 128);
  if (ihp == 0 || ihp == XP - 1) {
    const uint4 z = {0u, 0u, 0u, 0u};
    for (int i = t; i < XP * 16; i += 256) dst[i] = z;
    return;
  }
  const int ih = ihp - 1;
  const float4* src = (const float4*)(x + (bg * 128) * LOUT + ih * HO);
  for (int i = t; i < 128 * 14; i += 256) {
    int c = i / 14, seg = i - c * 14;                // iw = seg*4
    float4 v = src[c * (LOUT / 4) + seg];
    float* row = &lds[(seg * 4) * 129 + c];
    row[0]       = v.x;
    row[129]     = v.y;
    row[2 * 129] = v.z;
    row[3 * 129] = v.w;
  }
  __syncthreads();
  for (int i = t; i < XP * 16; i += 256) {
    int iwp = i >> 4, oct = i & 15;
    uint4 val = {0u, 0u, 0u, 0u};
    if (iwp != 0 && iwp != XP - 1) {
      const float* s = &lds[(iwp - 1) * 129 + (oct << 3)];
      val.x = (unsigned)f2bf(s[0]) | ((unsigned)f2bf(s[1]) << 16);
      val.y = (unsigned)f2bf(s[2]) | ((unsigned)f2bf(s[3]) << 16);
      val.z = (unsigned)f2bf(s[4]) | ((unsigned)f2bf(s[5]) << 16);
      val.w = (unsigned)f2bf(s[6]) | ((unsigned)f2bf(s[7]) << 16);
    }
    dst[i] = val;
  }
}

// ---------------- conv: implicit-GEMM, BK=64, xor-swizzled LDS ----------------
// LDS row = 64 c = 8 chunks of 16B; chunk (row,ch) stored at slot ch^(row&7).
// Staging: wave issue covers 8 rows x 8 chunks = 1 KB; lane l -> row +(l>>3),
// logical ch (l&7)^(l>>3)  (matches lane-linear LDS dest constraint).
__global__ __launch_bounds__(256, 4) void conv_mfma_kernel(
    const unsigned short* __restrict__ Wt, const unsigned short* __restrict__ Xt,
    float* __restrict__ out) {
  __shared__ __align__(16) unsigned short sA[128 * 64];   // 16 KB
  __shared__ __align__(16) unsigned short sB[128 * 64];   // 16 KB
  const int t  = threadIdx.x;
  const int ln = t & 63, wv = t >> 6;
  const int wm = wv >> 1, wn = wv & 1;
  const int col = ln & 15, kq = ln >> 4, c7 = col & 7;

  // XCD-aware swizzle: contiguous bg range per XCD for L2 locality
  const int lid   = blockIdx.y * 25 + blockIdx.x;
  const int v     = (lid & 7) * 200 + (lid >> 3);
  const int bg    = v / 25;
  const int tileN = v - bg * 25;
  const int g     = bg & 1;
  const int l0    = tileN << 7;

  // staging geometry (fixed per thread)
  const int r8 = ln >> 3;                  // row within 8-row issue group
  const int ch = (ln & 7) ^ r8;            // logical 16B chunk within 64-c row
  int arow[4], brow[4];
  #pragma unroll
  for (int i = 0; i < 4; ++i) {
    const int rr = (wv << 5) + (i << 3) + r8;      // 0..127
    arow[i] = (rr << 7) + (ch << 3);               // of*128 + c
    int ll = l0 + rr;
    if (ll > LOUT - 1) ll = LOUT - 1;              // tail tile: clamp
    int oh = ll / HO, ow = ll - oh * HO;
    brow[i] = ((bg * XP + oh) * XP + ow) * 128 + (ch << 3);
  }

  f32x4 acc[4][4];
  #pragma unroll
  for (int i = 0; i < 4; ++i)
    #pragma unroll
    for (int j = 0; j < 4; ++j) acc[i][j] = (f32x4){0.f, 0.f, 0.f, 0.f};

  for (int tap = 0; tap < 9; ++tap) {
    const int th = tap / 3, tw = tap - th * 3;
    const int bTap = (th * XP + tw) << 7;
    const int aTap = (g * 9 + tap) << 14;
    #pragma unroll 1
    for (int kc = 0; kc < 2; ++kc) {
      const int c0 = kc << 6;
      __syncthreads();                             // prior reads done
      #pragma unroll
      for (int i = 0; i < 4; ++i) {
        const int lb = ((wv << 5) + (i << 3)) << 6;   // LDS elem base
        async_load16(Wt + aTap + c0 + arow[i], &sA[lb]);
        async_load16(Xt + bTap + c0 + brow[i], &sB[lb]);
      }
      __syncthreads();                             // drains vmcnt
      #pragma unroll
      for (int kh = 0; kh < 2; ++kh) {
        const int pk = (((kh << 2) + kq) ^ c7) << 3;   // swizzled chunk offset
        bf16x8 af[4], bfr[4];
        #pragma unroll
        for (int mi = 0; mi < 4; ++mi)
          af[mi] = *(const bf16x8*)&sA[(((wm << 6) + (mi << 4) + col) << 6) + pk];
        #pragma unroll
        for (int ni = 0; ni < 4; ++ni)
          bfr[ni] = *(const bf16x8*)&sB[(((wn << 6) + (ni << 4) + col) << 6) + pk];
        #pragma unroll
        for (int mi = 0; mi < 4; ++mi)
          #pragma unroll
          for (int ni = 0; ni < 4; ++ni)
            acc[mi][ni] = __builtin_amdgcn_mfma_f32_16x16x32_bf16(
                af[mi], bfr[ni], acc[mi][ni], 0, 0, 0);
      }
    }
  }

  // epilogue: C/D layout col=lane&15, row=(lane>>4)*4+reg
  const int rowq = kq << 2;
  #pragma unroll
  for (int mi = 0; mi < 4; ++mi) {
    #pragma unroll
    for (int ni = 0; ni < 4; ++ni) {
      const int l = l0 + (wn << 6) + (ni << 4) + col;
      if (l < LOUT) {
        #pragma unroll
        for (int r = 0; r < 4; ++r) {
          const int of = (wm << 6) + (mi << 4) + rowq + r;
          out[(bg * 128 + of) * LOUT + l] = acc[mi][ni][r];
        }
      }
    }
  }
}

extern "C" void kernel_launch(void* const* d_in, const int* in_sizes, int n_in,
                              void* d_out, int out_size, void* d_ws, size_t ws_size,
                              hipStream_t stream) {
  const float* x   = (const float*)d_in[0];
  const float* Ws  = (const float*)d_in[1];
  const float* cw  = (const float*)d_in[2];
  const float* gb  = (const float*)d_in[3];
  const float* pat = (const float*)d_in[4];
  float* out = (float*)d_out;

  unsigned short* Wt = (unsigned short*)d_ws;                       // 576 KB
  unsigned short* Xt = (unsigned short*)((char*)d_ws + (1 << 20));  // 52.6 MB

  prep_kernel<<<4864, 256, 0, stream>>>(x, Ws, cw, gb, pat, Xt, Wt);
  conv_mfma_kernel<<<dim3(25, 64), 256, 0, stream>>>(Wt, Xt, out);
}